// Round 1
// baseline (19.860 us; speedup 1.0000x reference)
//
#include <hip/hip_runtime.h>

#define NPAIR (512 * 512)
#define NL 5
#define NH 8
#define ND 16
#define NE 10000
#define TPB 256
#define TROW (NL * NH)   // 40 floats per edge row in T

// Phase 1: T[e][l][h] = dot(F[e], W[1+l][h*16 .. h*16+15])
// One thread per (e, l): 400K/5 = 50000 (e,l) cells... k = e*5 + l, 8 dots of 16.
// 196 blocks, ~1 us. Output rows of 32B, consecutive threads -> coalesced stores.
__global__ __launch_bounds__(256) void build_table_kernel(
    const float* __restrict__ F,    // [E, D]
    const float* __restrict__ Wg,   // [L+1, H*D]
    float* __restrict__ T)          // [E, L, H]
{
    const int k = blockIdx.x * TPB + threadIdx.x;   // k = e*NL + l
    if (k >= NE * NL) return;
    const int e = k / NL;
    const int l = k - e * NL;

    const float4* __restrict__ fp = (const float4*)(F + (size_t)e * ND);
    const float4 f0 = fp[0], f1 = fp[1], f2 = fp[2], f3 = fp[3];

    const float* __restrict__ w0 = Wg + NH * ND + l * NH * ND;  // row 1+l of Wg

    float r[NH];
#pragma unroll
    for (int h = 0; h < NH; ++h) {
        const float4* __restrict__ wp = (const float4*)(w0 + h * ND);
        const float4 wa = wp[0], wb = wp[1], wc = wp[2], wd = wp[3];
        float a;
        a  = f0.x * wa.x + f0.y * wa.y + f0.z * wa.z + f0.w * wa.w;
        a += f1.x * wb.x + f1.y * wb.y + f1.z * wb.z + f1.w * wb.w;
        a += f2.x * wc.x + f2.y * wc.y + f2.z * wc.z + f2.w * wc.w;
        a += f3.x * wd.x + f3.y * wd.y + f3.z * wd.z + f3.w * wd.w;
        r[h] = a;
    }

    float4* __restrict__ tp = (float4*)(T + (size_t)k * NH);
    tp[0] = make_float4(r[0], r[1], r[2], r[3]);
    tp[1] = make_float4(r[4], r[5], r[6], r[7]);
}

// Phase 2: per pair p, gather 5 rows of T (32B each, L2-resident 1.6MB table),
// masked mean over l, write out[h, p].
// 2 lanes per pair (half = tid&1 owns h-chunk half*4..half*4+3): the two lanes'
// float4 loads are consecutive 16B of the same 32B row -> per-instruction
// coalescing merges them; ~320 line-lookups per 64 pairs vs 1280 before.
__global__ __launch_bounds__(256) void edge_sum_kernel(
    const int* __restrict__ sp,     // [NPAIR, L] int32
    const float* __restrict__ T,    // [E, L, H]
    float* __restrict__ out)        // [H, NPAIR]
{
    __shared__ int spL[128 * NL];   // 128 pairs * 5 ints = 2560B
    const int tid = threadIdx.x;
    const int base = blockIdx.x * 128;

    // stage 128 pairs * 5 ints = 160 int4, fully coalesced
    const int4* __restrict__ spv = (const int4*)(sp + (size_t)base * NL);
    int4* spd = (int4*)spL;
    if (tid < (128 * NL) / 4) spd[tid] = spv[tid];
    __syncthreads();

    const int q = tid >> 1;         // pair within block
    const int half = tid & 1;       // which 4-h chunk

    // stride-5 LDS reads, 5 coprime 32 -> conflict-free; lane pairs broadcast
    int e[NL];
#pragma unroll
    for (int l = 0; l < NL; ++l) e[l] = spL[q * NL + l];

    float ax = 0.f, ay = 0.f, az = 0.f, aw = 0.f, cnt = 0.f;
#pragma unroll
    for (int l = 0; l < NL; ++l) {
        const int idx = (e[l] >= 0) ? e[l] : 0;
        const float4 v = *(const float4*)(T + (size_t)idx * TROW + l * NH + half * 4);
        const float m = (e[l] >= 0) ? 1.f : 0.f;
        cnt += m;
        ax += m * v.x; ay += m * v.y; az += m * v.z; aw += m * v.w;
    }

    const float r = 1.0f / fmaxf(cnt, 1.f);
    const size_t p = (size_t)base + q;
    const float res[4] = {ax * r, ay * r, az * r, aw * r};
    // store j: even lanes -> plane half*4+j pairs base..base+31 (128B seg),
    // odd lanes -> plane 4+j same range: 2 full 128B segments per instruction.
#pragma unroll
    for (int j = 0; j < 4; ++j)
        __builtin_nontemporal_store(res[j], out + (size_t)(half * 4 + j) * NPAIR + p);
}

extern "C" void kernel_launch(void* const* d_in, const int* in_sizes, int n_in,
                              void* d_out, int out_size, void* d_ws, size_t ws_size,
                              hipStream_t stream) {
    (void)in_sizes; (void)n_in; (void)out_size; (void)ws_size;
    const float* F  = (const float*)d_in[0];   // edge_features_s [E, D]
    const float* Wg = (const float*)d_in[1];   // edge_weights [L+1, H*D]
    const int*   sp = (const int*)d_in[2];     // shortest_path_edges [N, N, L] int32
    float* out = (float*)d_out;                // [H, N, N]
    float* T = (float*)d_ws;                   // [E, L, H] = 1.6 MB scratch

    const int grid1 = (NE * NL + TPB - 1) / TPB;   // 196 blocks
    build_table_kernel<<<grid1, TPB, 0, stream>>>(F, Wg, T);

    const int grid2 = NPAIR / 128;                 // 2048 blocks
    edge_sum_kernel<<<grid2, TPB, 0, stream>>>(sp, T, out);
}